// Round 1
// baseline (93.225 us; speedup 1.0000x reference)
//
#include <hip/hip_runtime.h>

// Ewald reciprocal: B=2, N=4096 atoms, NK=4096 k-vectors, all f32.
// out = concat(0.5*q*phi, phi), each B*N floats.

constexpr int B  = 2;
constexpr int N  = 4096;
constexpr int NK = 4096;
constexpr int TPB = 256;
constexpr int NSPLIT1 = 16;   // atom-axis split for structure-factor pass
constexpr int NSPLIT2 = 16;   // k-axis split for field pass

// workspace layout (floats)
constexpr int KT_OFF  = 0;                    // NK*3   : kt[k] = cell_inv^T kvec[k]
constexpr int SRE_OFF = NK * 3;               // B*NK
constexpr int SIM_OFF = SRE_OFF + B * NK;     // B*NK
constexpr int REC_OFF = SIM_OFF + B * NK;     // B*N
constexpr int WS_FLOATS = REC_OFF + B * N;

__global__ __launch_bounds__(256) void prep_kt(const float* __restrict__ kvec,
                                               const float* __restrict__ cinv,
                                               float* __restrict__ ws) {
    int k = blockIdx.x * TPB + threadIdx.x;
    if (k >= NK) return;
    float k0 = kvec[k * 3 + 0], k1 = kvec[k * 3 + 1], k2 = kvec[k * 3 + 2];
    // kt[j] = sum_i kvec[k,i] * cinv[i,j]   (theta/2pi = kt . coord)
    ws[KT_OFF + k * 3 + 0] = fmaf(k0, cinv[0], fmaf(k1, cinv[3], k2 * cinv[6]));
    ws[KT_OFF + k * 3 + 1] = fmaf(k0, cinv[1], fmaf(k1, cinv[4], k2 * cinv[7]));
    ws[KT_OFF + k * 3 + 2] = fmaf(k0, cinv[2], fmaf(k1, cinv[5], k2 * cinv[8]));
}

// Pass 1: S_re[b,k] = sum_n q*cos(theta), S_im[b,k] = sum_n q*sin(theta)
// grid: (NK/TPB, NSPLIT1, B); each thread owns one k, loops over an atom chunk.
__global__ __launch_bounds__(256) void sf_kernel(const float* __restrict__ coords,
                                                 const float* __restrict__ q,
                                                 float* __restrict__ ws) {
    const int b = blockIdx.z;
    const int k = blockIdx.x * TPB + threadIdx.x;
    const int chunk = N / NSPLIT1;
    const int n0 = blockIdx.y * chunk;
    const float* cb = coords + (size_t)b * N * 3;
    const float* qb = q + (size_t)b * N;

    const float kt0 = ws[KT_OFF + k * 3 + 0];
    const float kt1 = ws[KT_OFF + k * 3 + 1];
    const float kt2 = ws[KT_OFF + k * 3 + 2];

    __shared__ float sc[TPB * 3];
    __shared__ float sq[TPB];

    float sre0 = 0.f, sre1 = 0.f, sim0 = 0.f, sim1 = 0.f;

    for (int t0 = 0; t0 < chunk; t0 += TPB) {
        const int base = n0 + t0;
        __syncthreads();
        sq[threadIdx.x] = qb[base + threadIdx.x];
#pragma unroll
        for (int j = 0; j < 3; ++j)
            sc[j * TPB + threadIdx.x] = cb[(size_t)base * 3 + j * TPB + threadIdx.x];
        __syncthreads();
#pragma unroll 8
        for (int i = 0; i < TPB; i += 2) {
            {
                float x = sc[3 * i + 0], y = sc[3 * i + 1], z = sc[3 * i + 2];
                float rev = fmaf(kt0, x, fmaf(kt1, y, kt2 * z));
                float r = rev - floorf(rev);
                float sn = __builtin_amdgcn_sinf(r);
                float cs = __builtin_amdgcn_cosf(r);
                float qv = sq[i];
                sre0 = fmaf(qv, cs, sre0);
                sim0 = fmaf(qv, sn, sim0);
            }
            {
                float x = sc[3 * i + 3], y = sc[3 * i + 4], z = sc[3 * i + 5];
                float rev = fmaf(kt0, x, fmaf(kt1, y, kt2 * z));
                float r = rev - floorf(rev);
                float sn = __builtin_amdgcn_sinf(r);
                float cs = __builtin_amdgcn_cosf(r);
                float qv = sq[i + 1];
                sre1 = fmaf(qv, cs, sre1);
                sim1 = fmaf(qv, sn, sim1);
            }
        }
    }
    atomicAdd(&ws[SRE_OFF + b * NK + k], sre0 + sre1);
    atomicAdd(&ws[SIM_OFF + b * NK + k], sim0 + sim1);
}

// Pass 2: recip[b,n] = sum_k expfac[k]*(S_re[b,k]*cos + S_im[b,k]*sin)
// grid: (N/TPB, NSPLIT2, B); each thread owns one atom, loops over a k chunk.
__global__ __launch_bounds__(256) void recip_kernel(const float* __restrict__ coords,
                                                    const float* __restrict__ expfac,
                                                    float* __restrict__ ws) {
    const int b = blockIdx.z;
    const int n = blockIdx.x * TPB + threadIdx.x;
    const int chunk = NK / NSPLIT2;
    const int k0 = blockIdx.y * chunk;

    const float* cp = coords + ((size_t)b * N + n) * 3;
    const float x = cp[0], y = cp[1], z = cp[2];

    __shared__ float skt[TPB * 3];
    __shared__ float sre[TPB];
    __shared__ float sim[TPB];

    float acc0 = 0.f, acc1 = 0.f;

    for (int t0 = 0; t0 < chunk; t0 += TPB) {
        const int kb = k0 + t0;
        const int t = threadIdx.x;
        __syncthreads();
        {
            float ef = expfac[kb + t];
            sre[t] = ef * ws[SRE_OFF + b * NK + kb + t];
            sim[t] = ef * ws[SIM_OFF + b * NK + kb + t];
#pragma unroll
            for (int j = 0; j < 3; ++j)
                skt[j * TPB + t] = ws[KT_OFF + (size_t)kb * 3 + j * TPB + t];
        }
        __syncthreads();
#pragma unroll 8
        for (int i = 0; i < TPB; i += 2) {
            {
                float kt0 = skt[3 * i + 0], kt1 = skt[3 * i + 1], kt2 = skt[3 * i + 2];
                float rev = fmaf(kt0, x, fmaf(kt1, y, kt2 * z));
                float r = rev - floorf(rev);
                float sn = __builtin_amdgcn_sinf(r);
                float cs = __builtin_amdgcn_cosf(r);
                acc0 = fmaf(sre[i], cs, fmaf(sim[i], sn, acc0));
            }
            {
                float kt0 = skt[3 * i + 3], kt1 = skt[3 * i + 4], kt2 = skt[3 * i + 5];
                float rev = fmaf(kt0, x, fmaf(kt1, y, kt2 * z));
                float r = rev - floorf(rev);
                float sn = __builtin_amdgcn_sinf(r);
                float cs = __builtin_amdgcn_cosf(r);
                acc1 = fmaf(sre[i + 1], cs, fmaf(sim[i + 1], sn, acc1));
            }
        }
    }
    atomicAdd(&ws[REC_OFF + b * N + n], acc0 + acc1);
}

__global__ __launch_bounds__(256) void final_kernel(const float* __restrict__ q,
                                                    const float* __restrict__ volume,
                                                    const float* __restrict__ bewald,
                                                    const float* __restrict__ ws,
                                                    float* __restrict__ out) {
    int i = blockIdx.x * TPB + threadIdx.x;
    if (i >= B * N) return;
    const float BOHRf = 1.8897261258369282f;
    const float PIf = 3.14159265358979323846f;
    const float inv_sqrt_pi = 0.5641895835477563f;
    float scale = BOHRf / (PIf * volume[0]);
    float self = 2.0f * bewald[0] * BOHRf * inv_sqrt_pi;
    float qv = q[i];
    float phi = ws[REC_OFF + i] * scale - qv * self;
    out[i] = 0.5f * qv * phi;
    out[B * N + i] = phi;
}

extern "C" void kernel_launch(void* const* d_in, const int* in_sizes, int n_in,
                              void* d_out, int out_size, void* d_ws, size_t ws_size,
                              hipStream_t stream) {
    const float* coords = (const float*)d_in[0];   // (B,N,3)
    const float* q      = (const float*)d_in[1];   // (B,N)
    const float* cinv   = (const float*)d_in[2];   // (3,3)
    const float* kvec   = (const float*)d_in[3];   // (NK,3)
    const float* expfac = (const float*)d_in[4];   // (NK,)
    const float* volume = (const float*)d_in[5];   // (1,)
    const float* bewald = (const float*)d_in[6];   // (1,)
    float* out = (float*)d_out;
    float* ws  = (float*)d_ws;

    // zero the accumulator regions (S_re, S_im, recip)
    hipMemsetAsync(ws + SRE_OFF, 0, (size_t)(WS_FLOATS - SRE_OFF) * sizeof(float), stream);

    prep_kt<<<dim3(NK / TPB), dim3(TPB), 0, stream>>>(kvec, cinv, ws);
    sf_kernel<<<dim3(NK / TPB, NSPLIT1, B), dim3(TPB), 0, stream>>>(coords, q, ws);
    recip_kernel<<<dim3(N / TPB, NSPLIT2, B), dim3(TPB), 0, stream>>>(coords, expfac, ws);
    final_kernel<<<dim3((B * N + TPB - 1) / TPB), dim3(TPB), 0, stream>>>(q, volume, bewald, ws, out);
}